// Round 10
// baseline (1054.349 us; speedup 1.0000x reference)
//
#include <hip/hip_runtime.h>
#include <math.h>

#define NB 2
#define NH 16
#define LSEQ 2048
#define DD 64
#define HSZ (LSEQ*DD)            // 131072 elements per (b,h)
#define NELEM (NB*NH*HSZ)        // 4194304 per tensor
#define NSLICE 4

typedef _Float16 half_t;
typedef _Float16 f16x4 __attribute__((ext_vector_type(4)));
typedef _Float16 f16x8 __attribute__((ext_vector_type(8)));
typedef float    f32x4 __attribute__((ext_vector_type(4)));
typedef int      i32x4 __attribute__((ext_vector_type(4)));

#define LGKM_BAR() do { \
    asm volatile("s_waitcnt lgkmcnt(0)" ::: "memory"); \
    __builtin_amdgcn_s_barrier(); } while (0)

// ---------------- K0a: q f32 -> f16 ----------------
__global__ __launch_bounds__(256) void convert_q(
    const float* __restrict__ q, half_t* __restrict__ qh)
{
    const int n4 = NELEM / 4;
    for (int gid = blockIdx.x * 256 + threadIdx.x; gid < n4; gid += gridDim.x * 256) {
        f32x4 x = __builtin_nontemporal_load((const f32x4*)q + gid);
        f16x4 y;
        y[0] = (half_t)x[0]; y[1] = (half_t)x[1]; y[2] = (half_t)x[2]; y[3] = (half_t)x[3];
        ((f16x4*)qh)[gid] = y;
    }
}

// ---------------- K0b: transpose+convert K-view and V ----------------
__global__ __launch_bounds__(256) void transpose_cvt(
    const float* __restrict__ k, const float* __restrict__ v,
    half_t* __restrict__ kt, half_t* __restrict__ vt)
{
    __shared__ half_t lds[64][72];
    const int tid = threadIdx.x;
    const int bh  = blockIdx.y;
    const int t64 = blockIdx.x;      // 0..31
    const float* src; half_t* dst; int C, R, r0, c0;
    if (blockIdx.z == 0) {
        src = k + (size_t)bh * HSZ; dst = kt + (size_t)bh * HSZ;
        R = 64; C = LSEQ; r0 = 0; c0 = t64 * 64;
    } else {
        src = v + (size_t)bh * HSZ; dst = vt + (size_t)bh * HSZ;
        R = LSEQ; C = 64; r0 = t64 * 64; c0 = 0;
    }
    const int rr = tid & 63, w4 = tid >> 6;
    #pragma unroll
    for (int qq = 0; qq < 4; ++qq) {
        f32x4 x = __builtin_nontemporal_load(
            (const f32x4*)&src[(size_t)(r0 + rr) * C + c0 + w4 * 16 + qq * 4]);
        lds[w4 * 16 + qq * 4 + 0][rr] = (half_t)x[0];
        lds[w4 * 16 + qq * 4 + 1][rr] = (half_t)x[1];
        lds[w4 * 16 + qq * 4 + 2][rr] = (half_t)x[2];
        lds[w4 * 16 + qq * 4 + 3][rr] = (half_t)x[3];
    }
    __syncthreads();
    #pragma unroll
    for (int p = 0; p < 2; ++p) {
        const int id = tid + p * 256;
        const int cl = id >> 3, rc = id & 7;
        f16x8 y = *(const f16x8*)&lds[cl][rc * 8];
        *(f16x8*)&dst[(size_t)(c0 + cl) * R + r0 + rc * 8] = y;
    }
}

// ------ Fused (j-sliced): QK^T + head-softmax + score store + partial PV -----
// r7 structure; LDS shrunk to 18.4 KB by overlapping red (8.7 KB, single
// buffer) with pbuf (18.4 KB) and sequencing with 3 lgkm-barriers per t.
// VGPR=64 + 18.4 KB LDS -> 8 blocks/CU = 32 waves/CU (2x r7's TLP).
__global__ __launch_bounds__(256, 8) void fused_attn_part(
    const half_t* __restrict__ qh, const half_t* __restrict__ kt,
    const half_t* __restrict__ vt, const int* __restrict__ mask,
    float* __restrict__ score, float* __restrict__ pout)
{
    __shared__ char smem_raw[18432];
    float*  red  = (float*)smem_raw;                 // 2176 f32 = 8704 B (overlaps pbuf)
    half_t* pbuf = (half_t*)smem_raw;                // 16 slots x [16 i][36] f16 = 18432 B
    const int tid = threadIdx.x, w = tid >> 6, lane = tid & 63;
    const int n16 = lane & 15, g = lane >> 4;
    const int g4 = g * 4, g8 = g * 8;

    const int bid = blockIdx.x;
    const int xcd = bid & 7;                  // one (b,jslice) group per XCD
    const int b      = xcd >> 2;
    const int jslice = xcd & 3;
    const int i0 = (bid >> 3) * 16;
    const int t0 = jslice * 16;               // j-steps t0..t0+15

    const size_t hb0 = (size_t)b * NH;
    const int h0 = w * 4;
    const int irow = i0 + n16;

    // hoisted q B-frags (loop-invariant)
    f16x8 qf[4][2];
    #pragma unroll
    for (int hh = 0; hh < 4; ++hh)
        #pragma unroll
        for (int kg = 0; kg < 2; ++kg)
            qf[hh][kg] = *(const f16x8*)(qh + (hb0 + h0 + hh) * (size_t)HSZ
                                         + (size_t)irow * DD + kg * 32 + g8);

    f32x4 acc[4][4];  // [head][d-subtile] partial out^T
    #pragma unroll
    for (int hh = 0; hh < 4; ++hh)
        #pragma unroll
        for (int ds = 0; ds < 4; ++ds) { acc[hh][ds][0]=0.f; acc[hh][ds][1]=0.f; acc[hh][ds][2]=0.f; acc[hh][ds][3]=0.f; }

    const int* mrow = mask + ((size_t)b * LSEQ + irow) * LSEQ;

    for (int t = t0; t < t0 + 16; ++t) {
        const int j0 = t * 32;
        i32x4 m0 = __builtin_nontemporal_load((const i32x4*)(mrow + j0 + g4));
        i32x4 m1 = __builtin_nontemporal_load((const i32x4*)(mrow + j0 + 16 + g4));
        int mvv[2][4] = {{m0[0], m0[1], m0[2], m0[3]}, {m1[0], m1[1], m1[2], m1[3]}};

        // ---- S^T tiles for this wave's 4 heads
        f32x4 sc[4][2];
        #pragma unroll
        for (int hh = 0; hh < 4; ++hh) {
            const half_t* kp = kt + (hb0 + h0 + hh) * (size_t)HSZ;
            #pragma unroll
            for (int jb = 0; jb < 2; ++jb) {
                const half_t* kr = kp + (size_t)(j0 + jb * 16 + n16) * DD;
                f16x8 k0 = *(const f16x8*)(kr + g8);
                f16x8 k1 = *(const f16x8*)(kr + 32 + g8);
                f32x4 c = {0.f, 0.f, 0.f, 0.f};
                c = __builtin_amdgcn_mfma_f32_16x16x32_f16(k0, qf[hh][0], c, 0, 0, 0);
                c = __builtin_amdgcn_mfma_f32_16x16x32_f16(k1, qf[hh][1], c, 0, 0, 0);
                sc[hh][jb] = c;
            }
        }

        // ---- exp (no max-subtract; masked -> e=1 for all heads => P=1/16)
        f32x4 ps[2] = {{0.f,0.f,0.f,0.f}, {0.f,0.f,0.f,0.f}};
        #pragma unroll
        for (int hh = 0; hh < 4; ++hh)
            #pragma unroll
            for (int jb = 0; jb < 2; ++jb)
                #pragma unroll
                for (int r = 0; r < 4; ++r) {
                    float e = (mvv[jb][r] == 0) ? 1.0f : __expf(0.125f * sc[hh][jb][r]);
                    sc[hh][jb][r] = e;
                    ps[jb][r] += e;
                }

        // ---- cross-wave sum; red single-buffered (overlaps pbuf region);
        //      previous iteration's barrier C guarantees it's free.
        #pragma unroll
        for (int jb = 0; jb < 2; ++jb)
            #pragma unroll
            for (int r = 0; r < 4; ++r)
                red[((jb * 16 + g4 + r) * 4 + w) * 17 + n16] = ps[jb][r];
        LGKM_BAR();                               // A: red ready

        float inv_[2][4];
        #pragma unroll
        for (int jb = 0; jb < 2; ++jb)
            #pragma unroll
            for (int r = 0; r < 4; ++r) {
                const int jc = (jb * 16 + g4 + r) * 4;
                float s = red[(jc + 0) * 17 + n16] + red[(jc + 1) * 17 + n16]
                        + red[(jc + 2) * 17 + n16] + red[(jc + 3) * 17 + n16];
                inv_[jb][r] = 1.0f / s;
            }
        LGKM_BAR();                               // B: red consumed; pbuf writes may begin

        // ---- P: stash f16 in per-wave pbuf slot + PV accumulate from regs
        #pragma unroll
        for (int hh = 0; hh < 4; ++hh) {
            half_t* pb_head = pbuf + (size_t)(w * 4 + hh) * 16 * 36;
            const half_t* vp = vt + (hb0 + h0 + hh) * (size_t)HSZ;
            #pragma unroll
            for (int jb = 0; jb < 2; ++jb) {
                f16x4 pb;
                #pragma unroll
                for (int r = 0; r < 4; ++r) pb[r] = (half_t)(sc[hh][jb][r] * inv_[jb][r]);
                *(f16x4*)(pb_head + n16 * 36 + jb * 16 + g4) = pb;  // 8B-aligned (stride 72B)
                #pragma unroll
                for (int ds = 0; ds < 4; ++ds) {
                    f16x4 av = *(const f16x4*)(vp + (size_t)(ds * 16 + n16) * LSEQ + j0 + jb * 16 + g4);
                    acc[hh][ds] = __builtin_amdgcn_mfma_f32_16x16x16f16(av, pb, acc[hh][ds], 0, 0, 0);
                }
            }
        }

        // ---- score store: full-128B-line nontemporal (wave-private pbuf)
        const int srow_ = lane >> 3, scol = (lane & 7) * 4;
        #pragma unroll
        for (int hh = 0; hh < 4; ++hh) {
            const half_t* pb_head = pbuf + (size_t)(w * 4 + hh) * 16 * 36;
            float* sbase = score + ((hb0 + h0 + hh) * LSEQ + i0) * LSEQ + j0;
            #pragma unroll
            for (int half_i = 0; half_i < 2; ++half_i) {
                const int row = half_i * 8 + srow_;
                f16x4 x = *(const f16x4*)(pb_head + row * 36 + scol);
                f32x4 y;
                y[0] = (float)x[0]; y[1] = (float)x[1]; y[2] = (float)x[2]; y[3] = (float)x[3];
                __builtin_nontemporal_store(y, (f32x4*)(sbase + (size_t)row * LSEQ + scol));
            }
        }
        LGKM_BAR();                               // C: pbuf reads done; red free next t
    }

    // ---- epilogue: wave-local LDS transpose of partial out^T -> full-line nt
    __syncthreads();
    float* pbase = pout + (size_t)jslice * NELEM;
    float* ep = (float*)smem_raw + w * 1088;   // 16 rows x stride 68 f32 (4x4352B)
    const int erow = lane >> 4, ecol = (lane & 15) * 4;
    #pragma unroll
    for (int hh = 0; hh < 4; ++hh) {
        #pragma unroll
        for (int ds = 0; ds < 4; ++ds)
            *(f32x4*)&ep[n16 * 68 + ds * 16 + g4] = acc[hh][ds];
        asm volatile("s_waitcnt lgkmcnt(0)" ::: "memory");
        float* obase = pbase + (hb0 + h0 + hh) * (size_t)HSZ + (size_t)i0 * DD;
        #pragma unroll
        for (int qq = 0; qq < 4; ++qq) {
            const int row = qq * 4 + erow;
            f32x4 x = *(const f32x4*)&ep[row * 68 + ecol];
            __builtin_nontemporal_store(x, (f32x4*)(obase + (size_t)row * DD + ecol));
        }
        asm volatile("s_waitcnt lgkmcnt(0)" ::: "memory");
    }
}

// ---------------- Reduce: out = sum of 4 partial slices ----------------
__global__ __launch_bounds__(256) void reduce_out(
    const float* __restrict__ pout, float* __restrict__ out)
{
    const int n4 = NELEM / 4;
    for (int i = blockIdx.x * 256 + threadIdx.x; i < n4; i += gridDim.x * 256) {
        f32x4 a = __builtin_nontemporal_load((const f32x4*)pout + i);
        f32x4 bb = __builtin_nontemporal_load((const f32x4*)(pout + NELEM) + i);
        f32x4 c = __builtin_nontemporal_load((const f32x4*)(pout + 2 * (size_t)NELEM) + i);
        f32x4 d = __builtin_nontemporal_load((const f32x4*)(pout + 3 * (size_t)NELEM) + i);
        __builtin_nontemporal_store(a + bb + c + d, (f32x4*)out + i);
    }
}

extern "C" void kernel_launch(void* const* d_in, const int* in_sizes, int n_in,
                              void* d_out, int out_size, void* d_ws, size_t ws_size,
                              hipStream_t stream) {
    const float* q    = (const float*)d_in[0];
    const float* k    = (const float*)d_in[1];
    const float* v    = (const float*)d_in[2];
    const int*   mask = (const int*)d_in[3];

    float* out   = (float*)d_out;
    float* score = out + (size_t)NB * NH * LSEQ * DD;

    half_t* qh   = (half_t*)d_ws;            // 8 MB
    half_t* kt   = qh + NELEM;               // 8 MB  kt[b,h][j][d]
    half_t* vt   = kt + NELEM;               // 8 MB  vt[b,h][d][j]
    float*  pout = (float*)(vt + NELEM);     // 4 x 16 MB partial outputs

    convert_q<<<2048, 256, 0, stream>>>(q, qh);
    transpose_cvt<<<dim3(32, NB * NH, 2), 256, 0, stream>>>(k, v, kt, vt);
    fused_attn_part<<<1024, 256, 0, stream>>>(qh, kt, vt, mask, score, pout);
    reduce_out<<<1024, 256, 0, stream>>>(pout, out);
}

// Round 11
// 578.532 us; speedup vs baseline: 1.8225x; 1.8225x over previous
//
#include <hip/hip_runtime.h>
#include <math.h>

#define NB 2
#define NH 16
#define LSEQ 2048
#define DD 64
#define HSZ (LSEQ*DD)            // 131072 elements per (b,h)
#define NELEM (NB*NH*HSZ)        // 4194304 per tensor
#define NSLICE 4

typedef _Float16 half_t;
typedef _Float16 f16x2 __attribute__((ext_vector_type(2)));
typedef _Float16 f16x4 __attribute__((ext_vector_type(4)));
typedef _Float16 f16x8 __attribute__((ext_vector_type(8)));
typedef float    f32x4 __attribute__((ext_vector_type(4)));
typedef int      i32x4 __attribute__((ext_vector_type(4)));

#define LGKM_BAR() do { \
    asm volatile("s_waitcnt lgkmcnt(0)" ::: "memory"); \
    __builtin_amdgcn_s_barrier(); } while (0)

union F2U { float2 f; unsigned long long u; };

// ---------------- K0a: q f32 -> f16 ----------------
__global__ __launch_bounds__(256) void convert_q(
    const float* __restrict__ q, half_t* __restrict__ qh)
{
    const int n4 = NELEM / 4;
    for (int gid = blockIdx.x * 256 + threadIdx.x; gid < n4; gid += gridDim.x * 256) {
        f32x4 x = __builtin_nontemporal_load((const f32x4*)q + gid);
        f16x4 y;
        y[0] = (half_t)x[0]; y[1] = (half_t)x[1]; y[2] = (half_t)x[2]; y[3] = (half_t)x[3];
        ((f16x4*)qh)[gid] = y;
    }
}

// ---------------- K0b: transpose+convert K-view and V ----------------
__global__ __launch_bounds__(256) void transpose_cvt(
    const float* __restrict__ k, const float* __restrict__ v,
    half_t* __restrict__ kt, half_t* __restrict__ vt)
{
    __shared__ half_t lds[64][72];
    const int tid = threadIdx.x;
    const int bh  = blockIdx.y;
    const int t64 = blockIdx.x;      // 0..31
    const float* src; half_t* dst; int C, R, r0, c0;
    if (blockIdx.z == 0) {
        src = k + (size_t)bh * HSZ; dst = kt + (size_t)bh * HSZ;
        R = 64; C = LSEQ; r0 = 0; c0 = t64 * 64;
    } else {
        src = v + (size_t)bh * HSZ; dst = vt + (size_t)bh * HSZ;
        R = LSEQ; C = 64; r0 = t64 * 64; c0 = 0;
    }
    const int rr = tid & 63, w4 = tid >> 6;
    #pragma unroll
    for (int qq = 0; qq < 4; ++qq) {
        f32x4 x = __builtin_nontemporal_load(
            (const f32x4*)&src[(size_t)(r0 + rr) * C + c0 + w4 * 16 + qq * 4]);
        lds[w4 * 16 + qq * 4 + 0][rr] = (half_t)x[0];
        lds[w4 * 16 + qq * 4 + 1][rr] = (half_t)x[1];
        lds[w4 * 16 + qq * 4 + 2][rr] = (half_t)x[2];
        lds[w4 * 16 + qq * 4 + 3][rr] = (half_t)x[3];
    }
    __syncthreads();
    #pragma unroll
    for (int p = 0; p < 2; ++p) {
        const int id = tid + p * 256;
        const int cl = id >> 3, rc = id & 7;
        f16x8 y = *(const f16x8*)&lds[cl][rc * 8];
        *(f16x8*)&dst[(size_t)(c0 + cl) * R + r0 + rc * 8] = y;
    }
}

// ------ Fused (j-sliced): QK^T + head-softmax + score store + partial PV -----
// r7 structure + (a) single-buffered red (27.1 KB LDS -> 6 blocks/CU),
// (b) score stores as 8B system-scope atomic stores (sc0 sc1: no L2
// allocate -> no read-for-ownership on the 512 MB score stream).
__global__ __launch_bounds__(256, 4) void fused_attn_part(
    const half_t* __restrict__ qh, const half_t* __restrict__ kt,
    const half_t* __restrict__ vt, const int* __restrict__ mask,
    float* __restrict__ score, float* __restrict__ pout)
{
    __shared__ char smem_raw[27136];
    float*  red  = (float*)smem_raw;                 // 2176 f32 = 8704 B (single buf)
    half_t* pbuf = (half_t*)(smem_raw + 8704);       // 16 slots x [16 i][36] f16 = 18432 B
    const int tid = threadIdx.x, w = tid >> 6, lane = tid & 63;
    const int n16 = lane & 15, g = lane >> 4;
    const int g4 = g * 4, g8 = g * 8;

    const int bid = blockIdx.x;
    const int xcd = bid & 7;                  // one (b,jslice) group per XCD
    const int b      = xcd >> 2;
    const int jslice = xcd & 3;
    const int i0 = (bid >> 3) * 16;
    const int t0 = jslice * 16;               // j-steps t0..t0+15

    const size_t hb0 = (size_t)b * NH;
    const int h0 = w * 4;
    const int irow = i0 + n16;

    // hoisted q B-frags (loop-invariant)
    f16x8 qf[4][2];
    #pragma unroll
    for (int hh = 0; hh < 4; ++hh)
        #pragma unroll
        for (int kg = 0; kg < 2; ++kg)
            qf[hh][kg] = *(const f16x8*)(qh + (hb0 + h0 + hh) * (size_t)HSZ
                                         + (size_t)irow * DD + kg * 32 + g8);

    f32x4 acc[4][4];  // [head][d-subtile] partial out^T
    #pragma unroll
    for (int hh = 0; hh < 4; ++hh)
        #pragma unroll
        for (int ds = 0; ds < 4; ++ds) { acc[hh][ds][0]=0.f; acc[hh][ds][1]=0.f; acc[hh][ds][2]=0.f; acc[hh][ds][3]=0.f; }

    const int* mrow = mask + ((size_t)b * LSEQ + irow) * LSEQ;

    for (int t = t0; t < t0 + 16; ++t) {
        const int j0 = t * 32;
        i32x4 m0 = __builtin_nontemporal_load((const i32x4*)(mrow + j0 + g4));
        i32x4 m1 = __builtin_nontemporal_load((const i32x4*)(mrow + j0 + 16 + g4));
        int mvv[2][4] = {{m0[0], m0[1], m0[2], m0[3]}, {m1[0], m1[1], m1[2], m1[3]}};

        // ---- S^T tiles for this wave's 4 heads
        f32x4 sc[4][2];
        #pragma unroll
        for (int hh = 0; hh < 4; ++hh) {
            const half_t* kp = kt + (hb0 + h0 + hh) * (size_t)HSZ;
            #pragma unroll
            for (int jb = 0; jb < 2; ++jb) {
                const half_t* kr = kp + (size_t)(j0 + jb * 16 + n16) * DD;
                f16x8 k0 = *(const f16x8*)(kr + g8);
                f16x8 k1 = *(const f16x8*)(kr + 32 + g8);
                f32x4 c = {0.f, 0.f, 0.f, 0.f};
                c = __builtin_amdgcn_mfma_f32_16x16x32_f16(k0, qf[hh][0], c, 0, 0, 0);
                c = __builtin_amdgcn_mfma_f32_16x16x32_f16(k1, qf[hh][1], c, 0, 0, 0);
                sc[hh][jb] = c;
            }
        }

        // ---- exp (no max-subtract; masked -> e=1 for all heads => P=1/16)
        f32x4 ps[2] = {{0.f,0.f,0.f,0.f}, {0.f,0.f,0.f,0.f}};
        #pragma unroll
        for (int hh = 0; hh < 4; ++hh)
            #pragma unroll
            for (int jb = 0; jb < 2; ++jb)
                #pragma unroll
                for (int r = 0; r < 4; ++r) {
                    float e = (mvv[jb][r] == 0) ? 1.0f : __expf(0.125f * sc[hh][jb][r]);
                    sc[hh][jb][r] = e;
                    ps[jb][r] += e;
                }

        // ---- cross-wave sum (single-buffered red; barrier B of prev t freed it)
        #pragma unroll
        for (int jb = 0; jb < 2; ++jb)
            #pragma unroll
            for (int r = 0; r < 4; ++r)
                red[((jb * 16 + g4 + r) * 4 + w) * 17 + n16] = ps[jb][r];
        LGKM_BAR();                               // A: red ready

        float inv_[2][4];
        #pragma unroll
        for (int jb = 0; jb < 2; ++jb)
            #pragma unroll
            for (int r = 0; r < 4; ++r) {
                const int jc = (jb * 16 + g4 + r) * 4;
                float s = red[(jc + 0) * 17 + n16] + red[(jc + 1) * 17 + n16]
                        + red[(jc + 2) * 17 + n16] + red[(jc + 3) * 17 + n16];
                inv_[jb][r] = 1.0f / s;
            }
        LGKM_BAR();                               // B: red consumed -> free for next t

        // ---- P: stash f16 in per-wave pbuf slot + PV accumulate from regs
        //      (pbuf slots are wave-private: no barrier needed)
        #pragma unroll
        for (int hh = 0; hh < 4; ++hh) {
            half_t* pb_head = pbuf + (size_t)(w * 4 + hh) * 16 * 36;
            const half_t* vp = vt + (hb0 + h0 + hh) * (size_t)HSZ;
            #pragma unroll
            for (int jb = 0; jb < 2; ++jb) {
                f16x4 pb;
                #pragma unroll
                for (int r = 0; r < 4; ++r) pb[r] = (half_t)(sc[hh][jb][r] * inv_[jb][r]);
                *(f16x4*)(pb_head + n16 * 36 + jb * 16 + g4) = pb;  // 8B-aligned (stride 72B)
                #pragma unroll
                for (int ds = 0; ds < 4; ++ds) {
                    f16x4 av = *(const f16x4*)(vp + (size_t)(ds * 16 + n16) * LSEQ + j0 + jb * 16 + g4);
                    acc[hh][ds] = __builtin_amdgcn_mfma_f32_16x16x16f16(av, pb, acc[hh][ds], 0, 0, 0);
                }
            }
        }

        // ---- score store: 8B system-scope stores (sc0 sc1 -> no RFO),
        //      line-coherent: 16 lanes x 8B = 128B per row, 4 rows/instr
        const int srow8 = lane >> 4;          // 0..3
        const int scol8 = (lane & 15) * 2;    // float-pair column
        asm volatile("s_waitcnt lgkmcnt(0)" ::: "memory");   // pbuf writes visible to self
        #pragma unroll
        for (int hh = 0; hh < 4; ++hh) {
            const half_t* pb_head = pbuf + (size_t)(w * 4 + hh) * 16 * 36;
            float* sbase = score + ((hb0 + h0 + hh) * LSEQ + i0) * LSEQ + j0;
            #pragma unroll
            for (int rq = 0; rq < 4; ++rq) {
                const int row = rq * 4 + srow8;
                f16x2 x = *(const f16x2*)(pb_head + row * 36 + scol8);
                F2U u;
                u.f.x = (float)x[0];
                u.f.y = (float)x[1];
                __hip_atomic_store((unsigned long long*)(sbase + (size_t)row * LSEQ + scol8),
                                   u.u, __ATOMIC_RELAXED, __HIP_MEMORY_SCOPE_SYSTEM);
            }
        }
    }

    // ---- epilogue: wave-local LDS transpose of partial out^T -> full-line nt
    __syncthreads();
    float* pbase = pout + (size_t)jslice * NELEM;
    float* ep = (float*)smem_raw + w * 1088;   // 16 rows x stride 68 f32 (4x4352B)
    const int erow = lane >> 4, ecol = (lane & 15) * 4;
    #pragma unroll
    for (int hh = 0; hh < 4; ++hh) {
        #pragma unroll
        for (int ds = 0; ds < 4; ++ds)
            *(f32x4*)&ep[n16 * 68 + ds * 16 + g4] = acc[hh][ds];
        asm volatile("s_waitcnt lgkmcnt(0)" ::: "memory");
        float* obase = pbase + (hb0 + h0 + hh) * (size_t)HSZ + (size_t)i0 * DD;
        #pragma unroll
        for (int qq = 0; qq < 4; ++qq) {
            const int row = qq * 4 + erow;
            f32x4 x = *(const f32x4*)&ep[row * 68 + ecol];
            __builtin_nontemporal_store(x, (f32x4*)(obase + (size_t)row * DD + ecol));
        }
        asm volatile("s_waitcnt lgkmcnt(0)" ::: "memory");
    }
}

// ---------------- Reduce: out = sum of 4 partial slices ----------------
__global__ __launch_bounds__(256) void reduce_out(
    const float* __restrict__ pout, float* __restrict__ out)
{
    const int n4 = NELEM / 4;
    for (int i = blockIdx.x * 256 + threadIdx.x; i < n4; i += gridDim.x * 256) {
        f32x4 a = __builtin_nontemporal_load((const f32x4*)pout + i);
        f32x4 bb = __builtin_nontemporal_load((const f32x4*)(pout + NELEM) + i);
        f32x4 c = __builtin_nontemporal_load((const f32x4*)(pout + 2 * (size_t)NELEM) + i);
        f32x4 d = __builtin_nontemporal_load((const f32x4*)(pout + 3 * (size_t)NELEM) + i);
        __builtin_nontemporal_store(a + bb + c + d, (f32x4*)out + i);
    }
}

extern "C" void kernel_launch(void* const* d_in, const int* in_sizes, int n_in,
                              void* d_out, int out_size, void* d_ws, size_t ws_size,
                              hipStream_t stream) {
    const float* q    = (const float*)d_in[0];
    const float* k    = (const float*)d_in[1];
    const float* v    = (const float*)d_in[2];
    const int*   mask = (const int*)d_in[3];

    float* out   = (float*)d_out;
    float* score = out + (size_t)NB * NH * LSEQ * DD;

    half_t* qh   = (half_t*)d_ws;            // 8 MB
    half_t* kt   = qh + NELEM;               // 8 MB  kt[b,h][j][d]
    half_t* vt   = kt + NELEM;               // 8 MB  vt[b,h][d][j]
    float*  pout = (float*)(vt + NELEM);     // 4 x 16 MB partial outputs

    convert_q<<<2048, 256, 0, stream>>>(q, qh);
    transpose_cvt<<<dim3(32, NB * NH, 2), 256, 0, stream>>>(k, v, kt, vt);
    fused_attn_part<<<1024, 256, 0, stream>>>(qh, kt, vt, mask, score, pout);
    reduce_out<<<1024, 256, 0, stream>>>(pout, out);
}